// Round 11
// baseline (84.853 us; speedup 1.0000x reference)
//
#include <hip/hip_runtime.h>

// LNCC loss: I,J [16,1,768,768] f32 -> out [16] f32
// R11: wave-autonomous colsum-share via shuffles. Each lane owns 4 cols with
// the 5-channel running vertical colsums in registers (zero redundancy, like
// R10) but the horizontal 9-sum halo comes from __shfl_down prefix/suffix
// trees (5 bperm/channel) instead of LDS publish + barrier. NO LDS, NO
// barriers. 4 column bands of 248 outputs (4-col overlap). Bulk warmup loads
// (16 independent, not 8 serial chains). P/Q prefetch one full row ahead.
// Grid = 4096 waves = exactly 4/SIMD, zero tail.

constexpr int BATCH = 16;
constexpr int H = 768;
constexpr int W = 768;
constexpr float INV_WS = 1.0f / 81.0f;
constexpr float EPS = 3.0590232050182579e-07f;   // exp(-15)

constexpr int SEG = 12;                   // output rows per wave task
constexpr int NSEGV = H / SEG;            // 64
constexpr int NBAND = 4;                  // column bands
constexpr int BANDW = 248;                // output cols per band (bands 0-2)
constexpr int NTHREADS = 256;             // 4 waves = 4 tasks per block
constexpr int NTASKS = NBAND * NSEGV * BATCH;   // 4096
constexpr int NBLOCKS = NTASKS / 4;             // 1024

__global__ void zero_acc_kernel(float* acc) {
    if (threadIdx.x < BATCH) acc[threadIdx.x] = 0.0f;
}

#define F4SCALE(a, s)  { a.x *= (s); a.y *= (s); a.z *= (s); a.w *= (s); }
#define F4ADD(a, u)    { a.x += u.x; a.y += u.y; a.z += u.z; a.w += u.w; }
#define F4SUB(a, u)    { a.x -= u.x; a.y -= u.y; a.z -= u.z; a.w -= u.w; }
#define F4FMA(a, u, v) { a.x = fmaf(u.x, v.x, a.x); a.y = fmaf(u.y, v.y, a.y); \
                         a.z = fmaf(u.z, v.z, a.z); a.w = fmaf(u.w, v.w, a.w); }
#define F4FMS(a, u, v) { a.x = fmaf(u.x, -v.x, a.x); a.y = fmaf(u.y, -v.y, a.y); \
                         a.z = fmaf(u.z, -v.z, a.z); a.w = fmaf(u.w, -v.w, a.w); }

// h[e] = sum of 9 consecutive colsums starting at own col e:
// own suffix suf(e) (4-e terms) + lane l+1's total (4) + lane l+2's prefix(e) (e+1)
#define HSUM_SHFL(c, h)                                                   \
    {                                                                     \
        const float s3 = c.w;                                             \
        const float s2 = c.w + c.z;                                       \
        const float s1 = s2 + c.y;                                        \
        const float s0 = s1 + c.x;          /* own total */               \
        const float p1 = c.x + c.y;                                       \
        const float p2 = p1 + c.z;                                        \
        const float pn = __shfl_down(s0, 1, 64);                          \
        const float q0 = __shfl_down(c.x, 2, 64);                         \
        const float q1 = __shfl_down(p1, 2, 64);                          \
        const float q2 = __shfl_down(p2, 2, 64);                          \
        const float q3 = __shfl_down(s0, 2, 64);                          \
        h[0] = s0 + pn + q0;                                              \
        h[1] = s1 + pn + q1;                                              \
        h[2] = s2 + pn + q2;                                              \
        h[3] = s3 + pn + q3;                                              \
    }

__launch_bounds__(NTHREADS, 4)
__global__ void lncc_shfl(const float* __restrict__ gI, const float* __restrict__ gJ,
                          float* __restrict__ acc)
{
    const int lane = threadIdx.x & 63;
    const int task = blockIdx.x * 4 + (threadIdx.x >> 6);
    const int band = task & 3;
    const int seg  = (task >> 2) & 63;
    const int b    = task >> 8;
    const int r0   = seg * SEG;
    const int c0   = band * BANDW - 4 + 4 * lane;        // own cs base col
    const float fm = (c0 >= 0 && c0 + 3 < W) ? 1.0f : 0.0f;
    const int ca   = min(max(c0, 0), W - 4);             // 16B-aligned clamp
    const bool live = (lane <= 61) && (band * BANDW + 4 * lane + 3 < W);

    const float* __restrict__ Ib = gI + (size_t)b * (H * W);
    const float* __restrict__ Jb = gJ + (size_t)b * (H * W);

    float4 cs0 = {0,0,0,0}, cs1 = {0,0,0,0}, cs2 = {0,0,0,0},
           cs3 = {0,0,0,0}, cs4 = {0,0,0,0};

    // ---- warm-up: bulk-issue 16 independent loads (rows r0-4..r0+3), then add
    float4 Wi[8], Wj[8];
    #pragma unroll
    for (int k = 0; k < 8; ++k) {
        const int rr = r0 - 4 + k;               // <= 763, never >= H
        const int rc = max(rr, 0);
        Wi[k] = *(const float4*)(Ib + (size_t)rc * W + ca);
        Wj[k] = *(const float4*)(Jb + (size_t)rc * W + ca);
    }
    #pragma unroll
    for (int k = 0; k < 8; ++k) {
        const float s = (r0 - 4 + k >= 0) ? fm : 0.0f;
        float4 vi = Wi[k], vj = Wj[k];
        F4SCALE(vi, s) F4SCALE(vj, s)
        F4ADD(cs0, vi) F4ADD(cs1, vj)
        F4FMA(cs2, vi, vi) F4FMA(cs3, vj, vj) F4FMA(cs4, vi, vj)
    }

    // prefetch P for row r0: in-row r0+4 (< H always), out-row r0-4 = warmup[0]
    float4 Pii = *(const float4*)(Ib + (size_t)(r0 + 4) * W + ca);
    float4 Pij = *(const float4*)(Jb + (size_t)(r0 + 4) * W + ca);
    float4 Poi = Wi[0], Poj = Wj[0];

    float accum = 0.0f;

    // ---- main loop: one output row per iteration, no barriers ----
    #pragma unroll 1
    for (int r = r0; r < r0 + SEG; ++r) {
        // issue next row's 4 loads (consumed next iteration)
        const int rin = min(r + 5, H - 1);
        const int rot = max(r - 3, 0);
        const float4 Qii = *(const float4*)(Ib + (size_t)rin * W + ca);
        const float4 Qij = *(const float4*)(Jb + (size_t)rin * W + ca);
        const float4 Qoi = *(const float4*)(Ib + (size_t)rot * W + ca);
        const float4 Qoj = *(const float4*)(Jb + (size_t)rot * W + ca);

        const float si = (r + 4 < H)  ? fm : 0.0f;
        const float so = (r - 4 >= 0) ? fm : 0.0f;
        float4 vi = Pii, vj = Pij;
        F4SCALE(vi, si) F4SCALE(vj, si)

        // in-add: cs = 9-row colsums [r-4, r+4] for own 4 cols
        F4ADD(cs0, vi) F4ADD(cs1, vj)
        F4FMA(cs2, vi, vi) F4FMA(cs3, vj, vj) F4FMA(cs4, vi, vj)

        // horizontal 9-sums via shuffle prefix/suffix trees
        float hI[4], hJ[4], hII[4], hJJ[4], hIJ[4];
        HSUM_SHFL(cs0, hI)
        HSUM_SHFL(cs1, hJ)
        HSUM_SHFL(cs2, hII)
        HSUM_SHFL(cs3, hJJ)
        HSUM_SHFL(cs4, hIJ)

        // pixel math for own 4 output cols (col = c0+4+e)
        float rowsum = 0.0f;
        #pragma unroll
        for (int e = 0; e < 4; ++e) {
            const float u = -hI[e] * INV_WS;
            const float cross = fmaf(u, hJ[e], hIJ[e]);
            const float Ivar  = fmaf(u, hI[e], hII[e]);
            const float Jvar  = fmaf(-hJ[e] * INV_WS, hJ[e], hJJ[e]);
            float prod = Ivar * Jvar;
            float num  = cross * cross;
            if (!(prod > EPS)) { prod = 1.0f; num = 1.0f; }
            float inv_;
            asm("v_rcp_f32 %0, %1" : "=v"(inv_) : "v"(prod + EPS));
            rowsum = fmaf(num, inv_, rowsum);
        }
        accum += live ? rowsum : 0.0f;

        // out-sub: cs back to 8-row [r-3, r+4]
        float4 oi = Poi, oj = Poj;
        F4SCALE(oi, so) F4SCALE(oj, so)
        F4SUB(cs0, oi) F4SUB(cs1, oj)
        F4FMS(cs2, oi, oi) F4FMS(cs3, oj, oj) F4FMS(cs4, oi, oj)

        Pii = Qii; Pij = Qij; Poi = Qoi; Poj = Qoj;
    }

    // ---- wave reduction + one atomic per wave ----
    #pragma unroll
    for (int off = 32; off > 0; off >>= 1)
        accum += __shfl_xor(accum, off, 64);
    if (lane == 0) atomicAdd(&acc[b], accum);
}

__global__ void finalize_kernel(const float* __restrict__ acc, float* __restrict__ out) {
    if (threadIdx.x < BATCH)
        out[threadIdx.x] = 1.0f - acc[threadIdx.x] * (1.0f / (float)(H * W));
}

extern "C" void kernel_launch(void* const* d_in, const int* in_sizes, int n_in,
                              void* d_out, int out_size, void* d_ws, size_t ws_size,
                              hipStream_t stream) {
    const float* I = (const float*)d_in[0];
    const float* J = (const float*)d_in[1];
    float* out = (float*)d_out;
    float* acc = (float*)d_ws;

    zero_acc_kernel<<<1, 64, 0, stream>>>(acc);

    lncc_shfl<<<dim3(NBLOCKS), NTHREADS, 0, stream>>>(I, J, acc);  // 4096 waves

    finalize_kernel<<<1, 64, 0, stream>>>(acc, out);
}

// Round 12
// 53.183 us; speedup vs baseline: 1.5955x; 1.5955x over previous
//
#include <hip/hip_runtime.h>

// LNCC loss: I,J [16,1,768,768] f32 -> out [16] f32
// R12: 4-row batched steps. R11 post-mortem showed the 1-row P/Q prefetch
// never overlapped (compiler sinks the issue to the use; ~3800cy/row for
// 320cy VALU). Instead of fighting the scheduler, amortize: each step bulk-
// issues 16 INDEPENDENT float4 loads (4 in-rows + 4 out-rows x 2 images),
// then computes 4 rows back-to-back. Worst-case one vmcnt drain per step
// (~900cy) amortizes over 4 rows; 3 waves/SIMD cover the rest.
// Keeps R11's zero-redundancy colsums + shuffle hsum; no barriers in hot path.

constexpr int BATCH = 16;
constexpr int H = 768;
constexpr int W = 768;
constexpr float INV_WS = 1.0f / 81.0f;
constexpr float EPS = 3.0590232050182579e-07f;   // exp(-15)

constexpr int SEG = 12;                   // output rows per wave task
constexpr int NSEG = H / SEG;             // 64
constexpr int BANDW = 248;                // output cols per band
constexpr int NTHREADS = 256;             // 4 waves = 4 bands of one (seg,b)

__global__ void zero_acc_kernel(float* acc) {
    if (threadIdx.x < BATCH) acc[threadIdx.x] = 0.0f;
}

#define F4SCALE(a, s)  { a.x *= (s); a.y *= (s); a.z *= (s); a.w *= (s); }
#define F4ADD(a, u)    { a.x += u.x; a.y += u.y; a.z += u.z; a.w += u.w; }
#define F4SUB(a, u)    { a.x -= u.x; a.y -= u.y; a.z -= u.z; a.w -= u.w; }
#define F4FMA(a, u, v) { a.x = fmaf(u.x, v.x, a.x); a.y = fmaf(u.y, v.y, a.y); \
                         a.z = fmaf(u.z, v.z, a.z); a.w = fmaf(u.w, v.w, a.w); }
#define F4FMS(a, u, v) { a.x = fmaf(u.x, -v.x, a.x); a.y = fmaf(u.y, -v.y, a.y); \
                         a.z = fmaf(u.z, -v.z, a.z); a.w = fmaf(u.w, -v.w, a.w); }

// h[e] = sum of cs cols [c0+e, c0+e+8]; output col = c0+4+e = band*248+4*lane+e
#define HSUM_SHFL(c, h)                                                   \
    {                                                                     \
        const float s3 = c.w;                                             \
        const float s2 = c.w + c.z;                                       \
        const float s1 = s2 + c.y;                                        \
        const float s0 = s1 + c.x;          /* own total */               \
        const float p1 = c.x + c.y;                                       \
        const float p2 = p1 + c.z;                                        \
        const float pn = __shfl_down(s0, 1, 64);                          \
        const float q0 = __shfl_down(c.x, 2, 64);                         \
        const float q1 = __shfl_down(p1, 2, 64);                          \
        const float q2 = __shfl_down(p2, 2, 64);                          \
        const float q3 = __shfl_down(s0, 2, 64);                          \
        h[0] = s0 + pn + q0;                                              \
        h[1] = s1 + pn + q1;                                              \
        h[2] = s2 + pn + q2;                                              \
        h[3] = s3 + pn + q3;                                              \
    }

__launch_bounds__(NTHREADS, 3)
__global__ void lncc_b4(const float* __restrict__ gI, const float* __restrict__ gJ,
                        float* __restrict__ acc)
{
    __shared__ float wsum[4];

    const int lane = threadIdx.x & 63;
    const int band = threadIdx.x >> 6;                   // 0..3
    const int r0   = blockIdx.x * SEG;
    const int b    = blockIdx.y;
    const int c0   = band * BANDW - 4 + 4 * lane;        // own cs base col
    const float fm = (c0 >= 0 && c0 + 3 < W) ? 1.0f : 0.0f;
    const int ca   = min(max(c0, 0), W - 4);             // 16B-aligned clamp
    const bool live = (lane <= 61) && (band * BANDW + 4 * lane + 3 < W);

    const float* __restrict__ Ib = gI + (size_t)b * (H * W);
    const float* __restrict__ Jb = gJ + (size_t)b * (H * W);

    float4 cs0 = {0,0,0,0}, cs1 = {0,0,0,0}, cs2 = {0,0,0,0},
           cs3 = {0,0,0,0}, cs4 = {0,0,0,0};

    // ---- warm-up: rows r0-4 .. r0+3 in two bulk steps of 4 ----
    #pragma unroll
    for (int s = 0; s < 2; ++s) {
        float4 Vi[4], Vj[4];
        #pragma unroll
        for (int k = 0; k < 4; ++k) {
            const int rr = r0 - 4 + 4 * s + k;           // <= 759, never >= H
            const int rc = max(rr, 0);
            Vi[k] = *(const float4*)(Ib + (size_t)rc * W + ca);
            Vj[k] = *(const float4*)(Jb + (size_t)rc * W + ca);
        }
        #pragma unroll
        for (int k = 0; k < 4; ++k) {
            const float sm = (r0 - 4 + 4 * s + k >= 0) ? fm : 0.0f;
            float4 vi = Vi[k], vj = Vj[k];
            F4SCALE(vi, sm) F4SCALE(vj, sm)
            F4ADD(cs0, vi) F4ADD(cs1, vj)
            F4FMA(cs2, vi, vi) F4FMA(cs3, vj, vj) F4FMA(cs4, vi, vj)
        }
    }

    float accum = 0.0f;

    // ---- main loop: 3 steps of 4 output rows ----
    #pragma unroll 1
    for (int r = r0; r < r0 + SEG; r += 4) {
        // bulk-issue 16 independent loads for this step
        float4 Vi[4], Vj[4], Oi[4], Oj[4];
        #pragma unroll
        for (int k = 0; k < 4; ++k) {
            const int ri = min(r + 4 + k, H - 1);
            const int ro = max(r - 4 + k, 0);
            Vi[k] = *(const float4*)(Ib + (size_t)ri * W + ca);
            Vj[k] = *(const float4*)(Jb + (size_t)ri * W + ca);
            Oi[k] = *(const float4*)(Ib + (size_t)ro * W + ca);
            Oj[k] = *(const float4*)(Jb + (size_t)ro * W + ca);
        }

        // 4 rows of pure-VALU sliding-window compute
        #pragma unroll
        for (int k = 0; k < 4; ++k) {
            const float si = (r + 4 + k < H)  ? fm : 0.0f;
            const float so = (r - 4 + k >= 0) ? fm : 0.0f;

            float4 vi = Vi[k], vj = Vj[k];
            F4SCALE(vi, si) F4SCALE(vj, si)
            F4ADD(cs0, vi) F4ADD(cs1, vj)
            F4FMA(cs2, vi, vi) F4FMA(cs3, vj, vj) F4FMA(cs4, vi, vj)

            float hI[4], hJ[4], hII[4], hJJ[4], hIJ[4];
            HSUM_SHFL(cs0, hI)
            HSUM_SHFL(cs1, hJ)
            HSUM_SHFL(cs2, hII)
            HSUM_SHFL(cs3, hJJ)
            HSUM_SHFL(cs4, hIJ)

            float rowsum = 0.0f;
            #pragma unroll
            for (int e = 0; e < 4; ++e) {
                const float u = -hI[e] * INV_WS;
                const float cross = fmaf(u, hJ[e], hIJ[e]);
                const float Ivar  = fmaf(u, hI[e], hII[e]);
                const float Jvar  = fmaf(-hJ[e] * INV_WS, hJ[e], hJJ[e]);
                float prod = Ivar * Jvar;
                float num  = cross * cross;
                if (!(prod > EPS)) { prod = 1.0f; num = 1.0f; }
                float inv_;
                asm("v_rcp_f32 %0, %1" : "=v"(inv_) : "v"(prod + EPS));
                rowsum = fmaf(num, inv_, rowsum);
            }
            accum += live ? rowsum : 0.0f;

            float4 oi = Oi[k], oj = Oj[k];
            F4SCALE(oi, so) F4SCALE(oj, so)
            F4SUB(cs0, oi) F4SUB(cs1, oj)
            F4FMS(cs2, oi, oi) F4FMS(cs3, oj, oj) F4FMS(cs4, oi, oj)
        }
    }

    // ---- wave reduce -> block reduce -> one atomic per block ----
    #pragma unroll
    for (int off = 32; off > 0; off >>= 1)
        accum += __shfl_xor(accum, off, 64);
    if (lane == 0) wsum[band] = accum;
    __syncthreads();
    if (threadIdx.x == 0)
        atomicAdd(&acc[b], wsum[0] + wsum[1] + wsum[2] + wsum[3]);
}

__global__ void finalize_kernel(const float* __restrict__ acc, float* __restrict__ out) {
    if (threadIdx.x < BATCH)
        out[threadIdx.x] = 1.0f - acc[threadIdx.x] * (1.0f / (float)(H * W));
}

extern "C" void kernel_launch(void* const* d_in, const int* in_sizes, int n_in,
                              void* d_out, int out_size, void* d_ws, size_t ws_size,
                              hipStream_t stream) {
    const float* I = (const float*)d_in[0];
    const float* J = (const float*)d_in[1];
    float* out = (float*)d_out;
    float* acc = (float*)d_ws;

    zero_acc_kernel<<<1, 64, 0, stream>>>(acc);

    dim3 grid(NSEG, BATCH);   // 64 x 16 = 1024 blocks, 4096 waves
    lncc_b4<<<grid, NTHREADS, 0, stream>>>(I, J, acc);

    finalize_kernel<<<1, 64, 0, stream>>>(acc, out);
}